// Round 1
// baseline (615.237 us; speedup 1.0000x reference)
//
#include <hip/hip_runtime.h>
#include <hip/hip_bf16.h>

typedef __bf16 bf16;
typedef __attribute__((ext_vector_type(8))) __bf16 bf16x8;
typedef __attribute__((ext_vector_type(4))) float f32x4;

#define GLDS16(gp, lp) __builtin_amdgcn_global_load_lds( \
    (const __attribute__((address_space(1))) void*)(gp),  \
    (__attribute__((address_space(3))) void*)(lp), 16, 0, 0)

// ---------------------------------------------------------------------------
// Generic bf16 MFMA GEMM:  C[i][j] = sum_k A[i][k] * Bt[j][k]   (Bt = B^T)
// 128x128 tile, BK=32, 256 threads (4 waves, 2x2), 4x4 16x16 frags per wave.
// Batched via blockIdx.y; batch = (bb<<3)|bh with independent strides so
// attention (b,h) addressing works. M must be a multiple of 128; N guarded.
// EPI: 0 = store bf16; 1 = store f32 * scale; 2 = f32 residual dual-store;
//      3 = f32 bias + relu.
// ---------------------------------------------------------------------------
template<int EPI>
__global__ __launch_bounds__(256)
void gemm_bt(const bf16* __restrict__ A, int lda, long sAb, long sAh,
             const bf16* __restrict__ Bt, int ldb, long sBb, long sBh,
             void* __restrict__ Cp, int ldc, long sCb, long sCh,
             int M, int N, int K, int tilesN,
             const float* __restrict__ extra, float scale,
             float* __restrict__ C2)
{
    __shared__ __align__(16) bf16 Al[128 * 32];
    __shared__ __align__(16) bf16 Bl[128 * 32];

    const int t    = threadIdx.x;
    const int lane = t & 63;
    const int w    = t >> 6;
    const int wr   = w >> 1, wc = w & 1;
    const int bid  = blockIdx.x;
    const int batch = blockIdx.y;
    const int tm = bid / tilesN, tn = bid % tilesN;
    const int row0 = tm * 128, col0 = tn * 128;
    const int bb = batch >> 3, bh = batch & 7;

    const bf16* Ab = A  + (long)bb * sAb + (long)bh * sAh;
    const bf16* Bb = Bt + (long)bb * sBb + (long)bh * sBh;

    // staging: chunk q = pass*256 + t ; row = q>>2 ; col = (q&3)*8
    const int ar0 = t >> 2;
    const int ar1 = (t + 256) >> 2;
    const int ac  = (t & 3) * 8;
    bf16* AldsD0 = &Al[w * 512];
    bf16* AldsD1 = &Al[2048 + w * 512];
    bf16* BldsD0 = &Bl[w * 512];
    bf16* BldsD1 = &Bl[2048 + w * 512];

    const int arow0 = row0 + ar0, arow1 = row0 + ar1;
    int brow0 = col0 + ar0; if (brow0 > N - 1) brow0 = N - 1;  // N<128 guard (PV GEMM)
    int brow1 = col0 + ar1; if (brow1 > N - 1) brow1 = N - 1;

    f32x4 acc[4][4];
#pragma unroll
    for (int i = 0; i < 4; i++)
#pragma unroll
        for (int j = 0; j < 4; j++) acc[i][j] = (f32x4){0.f, 0.f, 0.f, 0.f};

    const int fr = lane & 15, hi = lane >> 4;

    for (int k0 = 0; k0 < K; k0 += 32) {
        GLDS16(Ab + (long)arow0 * lda + k0 + ac, AldsD0);
        GLDS16(Ab + (long)arow1 * lda + k0 + ac, AldsD1);
        GLDS16(Bb + (long)brow0 * ldb + k0 + ac, BldsD0);
        GLDS16(Bb + (long)brow1 * ldb + k0 + ac, BldsD1);
        asm volatile("s_waitcnt vmcnt(0)" ::: "memory");
        __syncthreads();

        bf16x8 af[4], bfr[4];
#pragma unroll
        for (int rt = 0; rt < 4; rt++)
            af[rt] = *(const bf16x8*)&Al[(wr * 64 + rt * 16 + fr) * 32 + hi * 8];
#pragma unroll
        for (int ct = 0; ct < 4; ct++)
            bfr[ct] = *(const bf16x8*)&Bl[(wc * 64 + ct * 16 + fr) * 32 + hi * 8];
#pragma unroll
        for (int rt = 0; rt < 4; rt++)
#pragma unroll
            for (int ct = 0; ct < 4; ct++)
                acc[rt][ct] = __builtin_amdgcn_mfma_f32_16x16x32_bf16(
                    af[rt], bfr[ct], acc[rt][ct], 0, 0, 0);
        __syncthreads();
    }

    const long cbase = (long)bb * sCb + (long)bh * sCh;
#pragma unroll
    for (int rt = 0; rt < 4; rt++) {
#pragma unroll
        for (int j = 0; j < 4; j++) {
            const int row = row0 + wr * 64 + rt * 16 + hi * 4 + j;
#pragma unroll
            for (int ct = 0; ct < 4; ct++) {
                const int col = col0 + wc * 64 + ct * 16 + fr;
                if (col < N) {
                    const float v = acc[rt][ct][j];
                    const long idx = cbase + (long)row * ldc + col;
                    if constexpr (EPI == 0) {
                        ((bf16*)Cp)[idx] = (bf16)v;
                    } else if constexpr (EPI == 1) {
                        ((float*)Cp)[idx] = v * scale;
                    } else if constexpr (EPI == 2) {
                        const float r = extra[idx] + v;
                        ((float*)Cp)[idx] = r;
                        C2[idx] = r;
                    } else {
                        const float r = v + extra[col];
                        ((float*)Cp)[idx] = r > 0.f ? r : 0.f;
                    }
                }
            }
        }
    }
}

// ---------------------------------------------------------------------------
// Elementwise f32 -> bf16 (4 per thread)
// ---------------------------------------------------------------------------
__global__ void cvt_f32_bf16(const float* __restrict__ in, bf16* __restrict__ out, int n4)
{
    const int i = blockIdx.x * 256 + threadIdx.x;
    if (i < n4) {
        const float4 v = *(const float4*)&in[(long)i * 4];
        union { bf16 h[4]; ushort4 u; } o;
        o.h[0] = (bf16)v.x; o.h[1] = (bf16)v.y; o.h[2] = (bf16)v.z; o.h[3] = (bf16)v.w;
        *(ushort4*)&out[(long)i * 4] = o.u;
    }
}

// ---------------------------------------------------------------------------
// Transpose + cvt for 512x512 fp32 weight matrices (W[c][j] -> Wt[j][c] bf16)
// z selects {Wq, Wk, Wv -> wqkv_t rows 0/512/1024 ; Wo -> wo_t}
// ---------------------------------------------------------------------------
__global__ __launch_bounds__(256)
void wtrans(const float* __restrict__ Wq, const float* __restrict__ Wk,
            const float* __restrict__ Wv, const float* __restrict__ Wo,
            bf16* __restrict__ wqkv_t, bf16* __restrict__ wo_t)
{
    __shared__ __align__(16) float T[64][68];
    const int z = blockIdx.z;
    const float* src = (z == 0) ? Wq : (z == 1) ? Wk : (z == 2) ? Wv : Wo;
    bf16* dst = (z < 3) ? (wqkv_t + (long)z * 262144) : wo_t;
    const int r0 = blockIdx.x * 64, c0 = blockIdx.y * 64;  // r0: c-dim, c0: j-dim
    const int t  = threadIdx.x;
    const int rl = t >> 2;
    const int cq = (t & 3) * 16;
#pragma unroll
    for (int i = 0; i < 4; i++) {
        const float4 v = *(const float4*)&src[(long)(r0 + rl) * 512 + c0 + cq + i * 4];
        T[cq + i * 4 + 0][rl] = v.x;
        T[cq + i * 4 + 1][rl] = v.y;
        T[cq + i * 4 + 2][rl] = v.z;
        T[cq + i * 4 + 3][rl] = v.w;
    }
    __syncthreads();
#pragma unroll
    for (int i = 0; i < 4; i++) {
        const float4 v = *(const float4*)&T[rl][cq + i * 4];
        union { bf16 h[4]; ushort4 u; } o;
        o.h[0] = (bf16)v.x; o.h[1] = (bf16)v.y; o.h[2] = (bf16)v.z; o.h[3] = (bf16)v.w;
        *(ushort4*)&dst[(long)(c0 + rl) * 512 + r0 + cq + i * 4] = o.u;
    }
}

// ---------------------------------------------------------------------------
// Transpose V region of qkv (bf16): vt[b*512 + (j-1024)][l] = qkv[b*256+l][j]
// 64x64 tiles. grid = (4 l-tiles, 8 j-tiles, 32 b)
// ---------------------------------------------------------------------------
__global__ __launch_bounds__(256)
void vtrans(const bf16* __restrict__ qkv, bf16* __restrict__ vt)
{
    __shared__ __align__(16) bf16 T[64][72];
    const int t  = threadIdx.x;
    const int l0 = blockIdx.x * 64, j0 = blockIdx.y * 64, b = blockIdx.z;
    const int r  = t >> 3;
    const int c8 = (t & 7) * 8;
#pragma unroll
    for (int p = 0; p < 2; p++) {
        const int rr = r + p * 32;
        bf16 v[8];
        *(uint4*)v = *(const uint4*)&qkv[(long)(b * 256 + l0 + rr) * 1536 + 1024 + j0 + c8];
#pragma unroll
        for (int i = 0; i < 8; i++) T[c8 + i][rr] = v[i];
    }
    __syncthreads();
#pragma unroll
    for (int p = 0; p < 2; p++) {
        const int rr = r + p * 32;  // local jv
        const uint4 val = *(const uint4*)&T[rr][c8];
        *(uint4*)&vt[(long)(b * 512 + j0 + rr) * 256 + l0 + c8] = val;
    }
}

// ---------------------------------------------------------------------------
// Row softmax over 256-wide rows: one wave per row. S f32 -> P bf16.
// ---------------------------------------------------------------------------
__global__ __launch_bounds__(256)
void softmax_rows(const float* __restrict__ S, bf16* __restrict__ P)
{
    const int row  = blockIdx.x * 4 + (threadIdx.x >> 6);
    const int lane = threadIdx.x & 63;
    const float4 v = *(const float4*)&S[(long)row * 256 + lane * 4];
    float m = fmaxf(fmaxf(v.x, v.y), fmaxf(v.z, v.w));
#pragma unroll
    for (int off = 1; off < 64; off <<= 1) m = fmaxf(m, __shfl_xor(m, off));
    const float e0 = __expf(v.x - m), e1 = __expf(v.y - m);
    const float e2 = __expf(v.z - m), e3 = __expf(v.w - m);
    float s = e0 + e1 + e2 + e3;
#pragma unroll
    for (int off = 1; off < 64; off <<= 1) s += __shfl_xor(s, off);
    const float inv = 1.0f / s;
    union { bf16 h[4]; ushort4 u; } o;
    o.h[0] = (bf16)(e0 * inv); o.h[1] = (bf16)(e1 * inv);
    o.h[2] = (bf16)(e2 * inv); o.h[3] = (bf16)(e3 * inv);
    *(ushort4*)&P[(long)row * 256 + lane * 4] = o.u;
}

// ---------------------------------------------------------------------------
// avg-pool along L (kernel=stride=k) ; sf [32][256][512] -> pooled [32][Ld][512]
// ---------------------------------------------------------------------------
__global__ void pool_k(const float* __restrict__ sf, float* __restrict__ pooled,
                       int ldshift, float invk)
{
    const int idx = blockIdx.x * 256 + threadIdx.x;
    const int c  = idx & 511;
    const int Ld = 1 << ldshift;
    const int k  = 256 >> ldshift;
    const int lp = (idx >> 9) & (Ld - 1);
    const int b  = idx >> (9 + ldshift);
    const float* p = sf + (long)(b * 256 + lp * k) * 512 + c;
    float s = 0.f;
    for (int i = 0; i < k; i++) s += p[(long)i * 512];
    pooled[idx] = s * invk;
}

// ---------------------------------------------------------------------------
// im2col (pad=1, kw=3): ic[b*Ld+l][ci*3+t] = pooled[b][l+t-1][ci] (bf16)
// ---------------------------------------------------------------------------
__global__ void im2col_k(const float* __restrict__ pooled, bf16* __restrict__ ic, int ldshift)
{
    const int idx = blockIdx.x * 256 + threadIdx.x;
    const int Ld  = 1 << ldshift;
    const unsigned col = (unsigned)idx % 1536u;
    const unsigned row = (unsigned)idx / 1536u;
    const unsigned ci  = col / 3u;
    const unsigned tt  = col - ci * 3u;
    const int l  = row & (Ld - 1);
    const int b  = (int)(row >> ldshift);
    const int ls = l + (int)tt - 1;
    const float v = ((unsigned)ls < (unsigned)Ld)
        ? pooled[(long)(b * Ld + ls) * 512 + ci] : 0.f;
    ic[idx] = (bf16)v;
}

// ---------------------------------------------------------------------------
// linear upsample (align_corners=False) + accumulate into sf ;
// LAST fuses final out = out_attn + sf + interp
// ---------------------------------------------------------------------------
template<int LAST>
__global__ void upsample_add(const float* __restrict__ conv, float* __restrict__ sf,
                             float* __restrict__ outp, int Ld, float scale)
{
    const int idx = blockIdx.x * 256 + threadIdx.x;
    const int c = idx & 511;
    const int j = (idx >> 9) & 255;
    const int b = idx >> 17;
    float coords = (j + 0.5f) * scale - 0.5f;
    coords = fminf(fmaxf(coords, 0.f), (float)(Ld - 1));
    const int lo = (int)coords;
    int hi = lo + 1; if (hi > Ld - 1) hi = Ld - 1;
    const float w = coords - (float)lo;
    const long rb = (long)b * Ld * 512 + c;
    const float v = conv[rb + (long)lo * 512] * (1.f - w)
                  + conv[rb + (long)hi * 512] * w;
    if (LAST) outp[idx] = outp[idx] + sf[idx] + v;
    else      sf[idx] += v;
}

// ---------------------------------------------------------------------------
// workspace layout (bytes)
// ---------------------------------------------------------------------------
static const long OFF_XB    = 0;          //  8,388,608  features bf16
static const long OFF_WQKV  = 8388608;    //  1,572,864  [1536][512] bf16
static const long OFF_WO    = 9961472;    //    524,288  [512][512] bf16
static const long OFF_WCONV = 10485760;   //  9,437,184  [6][512][1536] bf16
static const long OFF_QKV   = 19922944;   // 25,165,824  [8192][1536] bf16
static const long OFF_VT    = 45088768;   //  8,388,608  [32][512][256] bf16
static const long OFF_S     = 53477376;   // 67,108,864  [256][256][256] f32
static const long OFF_CTX   = 53477376;   //  (aliases S; S dead after softmax)
static const long OFF_POOL  = 61865984;   //  8,388,608  (aliases S region)
static const long OFF_IC    = 70254592;   // 12,582,912  (aliases S region)
static const long OFF_CONV  = 82837504;   //  8,388,608  (aliases S region)
static const long OFF_P     = 120586240;  // 33,554,432  [65536][256] bf16
static const long OFF_SF    = 154140672;  // 16,777,216  [8192][512] f32
// total: 170,917,888 bytes

extern "C" void kernel_launch(void* const* d_in, const int* in_sizes, int n_in,
                              void* d_out, int out_size, void* d_ws, size_t ws_size,
                              hipStream_t stream)
{
    const float* features = (const float*)d_in[0];
    const float* Wq = (const float*)d_in[1];
    const float* Wk = (const float*)d_in[2];
    const float* Wv = (const float*)d_in[3];
    const float* Wo = (const float*)d_in[4];
    const float* conv_w = (const float*)d_in[5];
    const float* conv_b = (const float*)d_in[6];
    float* out = (float*)d_out;

    char* ws = (char*)d_ws;
    bf16* xb     = (bf16*)(ws + OFF_XB);
    bf16* wqkv_t = (bf16*)(ws + OFF_WQKV);
    bf16* wo_t   = (bf16*)(ws + OFF_WO);
    bf16* wconv  = (bf16*)(ws + OFF_WCONV);
    bf16* qkv    = (bf16*)(ws + OFF_QKV);
    bf16* vt     = (bf16*)(ws + OFF_VT);
    float* Sbuf  = (float*)(ws + OFF_S);
    bf16* ctx    = (bf16*)(ws + OFF_CTX);
    float* pooled= (float*)(ws + OFF_POOL);
    bf16* ic     = (bf16*)(ws + OFF_IC);
    float* convo = (float*)(ws + OFF_CONV);
    bf16* P      = (bf16*)(ws + OFF_P);
    float* sf    = (float*)(ws + OFF_SF);

    // --- input conversions ---
    cvt_f32_bf16<<<4096, 256, 0, stream>>>(features, xb, 1048576);
    cvt_f32_bf16<<<4608, 256, 0, stream>>>(conv_w, wconv, 1179648);
    wtrans<<<dim3(8, 8, 4), 256, 0, stream>>>(Wq, Wk, Wv, Wo, wqkv_t, wo_t);

    // --- fused QKV projection: qkv[8192][1536] ---
    gemm_bt<0><<<dim3(768, 1), 256, 0, stream>>>(
        xb, 512, 0, 0, wqkv_t, 512, 0, 0, qkv, 1536, 0, 0,
        8192, 1536, 512, 12, nullptr, 1.f, nullptr);

    // --- V transpose for PV GEMM ---
    vtrans<<<dim3(4, 8, 32), 256, 0, stream>>>(qkv, vt);

    // --- scores: S[bh][l][m] = (q . k)/8 , batched over 256 (b,h) ---
    gemm_bt<1><<<dim3(4, 256), 256, 0, stream>>>(
        qkv, 1536, 393216, 64,           // A = q slice
        qkv + 512, 1536, 393216, 64,     // Bt = k slice (natural layout = K^T^T)
        Sbuf, 256, 524288, 65536,
        256, 256, 64, 2, nullptr, 0.125f, nullptr);

    // --- softmax rows -> P bf16 ---
    softmax_rows<<<16384, 256, 0, stream>>>(Sbuf, P);

    // --- ctx = P @ V : Bt = V^T (vt) ---
    gemm_bt<0><<<dim3(2, 256), 256, 0, stream>>>(
        P, 256, 524288, 65536,
        vt, 256, 131072, 16384,
        ctx, 512, 131072, 64,
        256, 64, 256, 1, nullptr, 1.f, nullptr);

    // --- out_attn = features + ctx @ Wo  (dual store: d_out and sf) ---
    gemm_bt<2><<<dim3(256, 1), 256, 0, stream>>>(
        ctx, 512, 0, 0, wo_t, 512, 0, 0, out, 512, 0, 0,
        8192, 512, 512, 4, features, 1.f, sf);

    // --- ScaleFeatures cascade (natural [B][L][C] layout; transposes cancel) ---
    for (int d = 0; d < 6; d++) {
        const int Ld = 128 >> d;           // pooled length
        const int k  = 2 << d;             // pool kernel
        const int ldshift = 7 - d;
        pool_k<<<Ld * 64, 256, 0, stream>>>(sf, pooled, ldshift, 1.0f / (float)k);
        im2col_k<<<Ld * 192, 256, 0, stream>>>(pooled, ic, ldshift);
        gemm_bt<3><<<dim3((Ld / 4) * 4, 1), 256, 0, stream>>>(
            ic, 1536, 0, 0,
            wconv + (long)d * 786432, 1536, 0, 0,
            convo, 512, 0, 0,
            32 * Ld, 512, 1536, 4, conv_b + d * 512, 1.f, nullptr);
        if (d < 5)
            upsample_add<0><<<16384, 256, 0, stream>>>(convo, sf, out, Ld, Ld / 256.f);
        else
            upsample_add<1><<<16384, 256, 0, stream>>>(convo, sf, out, Ld, Ld / 256.f);
    }
}

// Round 3
// 401.777 us; speedup vs baseline: 1.5313x; 1.5313x over previous
//
#include <hip/hip_runtime.h>
#include <hip/hip_bf16.h>

typedef __bf16 bf16;
typedef __attribute__((ext_vector_type(8))) __bf16 bf16x8;
typedef __attribute__((ext_vector_type(4))) float f32x4;

#define GLDS16(gp, lp) __builtin_amdgcn_global_load_lds( \
    (const __attribute__((address_space(1))) void*)(gp),  \
    (__attribute__((address_space(3))) void*)(lp), 16, 0, 0)

// ---------------------------------------------------------------------------
// Generic bf16 MFMA GEMM:  C[i][j] = sum_k A[i][k] * Bt[j][k]   (Bt = B^T)
// 128x128 tile, BK=32, 256 threads (4 waves, 2x2), 4x4 16x16 frags per wave.
// Double-buffered LDS, 2-phase pipeline: stage(t+1) issued before compute(t),
// single __syncthreads() per K-step (vmcnt(0) drain lands AFTER the MFMAs).
// blockIdx.y = batch ((bb<<3)|bh strides). blockIdx.z = K-split (chunk = KC).
// EPI: 0 = store bf16; 1 = store f32 * scale; 2 = f32 residual dual-store;
//      3 = f32 atomicAdd (split-K accumulate, bias/relu applied by consumer).
// ---------------------------------------------------------------------------
template<int EPI>
__global__ __launch_bounds__(256)
void gemm_bt(const bf16* __restrict__ A, int lda, long sAb, long sAh,
             const bf16* __restrict__ Bt, int ldb, long sBb, long sBh,
             void* __restrict__ Cp, int ldc, long sCb, long sCh,
             int M, int N, int KC, int tilesN,
             const float* __restrict__ extra, float scale,
             float* __restrict__ C2)
{
    __shared__ __align__(16) bf16 Al[2][128 * 32];
    __shared__ __align__(16) bf16 Bl[2][128 * 32];

    const int t    = threadIdx.x;
    const int lane = t & 63;
    const int w    = t >> 6;
    const int wr   = w >> 1, wc = w & 1;
    const int bid  = blockIdx.x;
    const int batch = blockIdx.y;
    const int tm = bid / tilesN, tn = bid % tilesN;
    const int row0 = tm * 128, col0 = tn * 128;
    const int bb = batch >> 3, bh = batch & 7;
    const int koff = blockIdx.z * KC;

    const bf16* Ab = A  + (long)bb * sAb + (long)bh * sAh;
    const bf16* Bb = Bt + (long)bb * sBb + (long)bh * sBh;

    // staging: chunk q = pass*256 + t ; row = q>>2 ; col = (q&3)*8
    const int ar0 = t >> 2;
    const int ar1 = (t + 256) >> 2;
    const int ac  = (t & 3) * 8;

    const int arow0 = row0 + ar0, arow1 = row0 + ar1;
    int brow0 = col0 + ar0; if (brow0 > N - 1) brow0 = N - 1;  // N<128 guard
    int brow1 = col0 + ar1; if (brow1 > N - 1) brow1 = N - 1;

    const long aoff0 = (long)arow0 * lda + koff + ac;
    const long aoff1 = (long)arow1 * lda + koff + ac;
    const long boff0 = (long)brow0 * ldb + koff + ac;
    const long boff1 = (long)brow1 * ldb + koff + ac;

    f32x4 acc[4][4];
#pragma unroll
    for (int i = 0; i < 4; i++)
#pragma unroll
        for (int j = 0; j < 4; j++) acc[i][j] = (f32x4){0.f, 0.f, 0.f, 0.f};

    const int fr = lane & 15, hi = lane >> 4;
    const int nt = KC >> 5;
    int cur = 0;

    // prologue: stage tile 0, drain, barrier
    GLDS16(Ab + aoff0, &Al[0][w * 512]);
    GLDS16(Ab + aoff1, &Al[0][2048 + w * 512]);
    GLDS16(Bb + boff0, &Bl[0][w * 512]);
    GLDS16(Bb + boff1, &Bl[0][2048 + w * 512]);
    __syncthreads();

    for (int tt = 0; tt < nt; ++tt) {
        if (tt + 1 < nt) {
            const int k1 = (tt + 1) * 32;
            GLDS16(Ab + aoff0 + k1, &Al[cur ^ 1][w * 512]);
            GLDS16(Ab + aoff1 + k1, &Al[cur ^ 1][2048 + w * 512]);
            GLDS16(Bb + boff0 + k1, &Bl[cur ^ 1][w * 512]);
            GLDS16(Bb + boff1 + k1, &Bl[cur ^ 1][2048 + w * 512]);
        }
        bf16x8 af[4], bfr[4];
#pragma unroll
        for (int rt = 0; rt < 4; rt++)
            af[rt] = *(const bf16x8*)&Al[cur][(wr * 64 + rt * 16 + fr) * 32 + hi * 8];
#pragma unroll
        for (int ct = 0; ct < 4; ct++)
            bfr[ct] = *(const bf16x8*)&Bl[cur][(wc * 64 + ct * 16 + fr) * 32 + hi * 8];
#pragma unroll
        for (int rt = 0; rt < 4; rt++)
#pragma unroll
            for (int ct = 0; ct < 4; ct++)
                acc[rt][ct] = __builtin_amdgcn_mfma_f32_16x16x32_bf16(
                    af[rt], bfr[ct], acc[rt][ct], 0, 0, 0);
        __syncthreads();   // drains vmcnt(0)+lgkmcnt(0): stage(t+1) complete
        cur ^= 1;
    }

    const long cbase = (long)bb * sCb + (long)bh * sCh;
#pragma unroll
    for (int rt = 0; rt < 4; rt++) {
#pragma unroll
        for (int j = 0; j < 4; j++) {
            const int row = row0 + wr * 64 + rt * 16 + hi * 4 + j;
#pragma unroll
            for (int ct = 0; ct < 4; ct++) {
                const int col = col0 + wc * 64 + ct * 16 + fr;
                if (col < N) {
                    const float v = acc[rt][ct][j];
                    const long idx = cbase + (long)row * ldc + col;
                    if constexpr (EPI == 0) {
                        ((bf16*)Cp)[idx] = (bf16)v;
                    } else if constexpr (EPI == 1) {
                        ((float*)Cp)[idx] = v * scale;
                    } else if constexpr (EPI == 2) {
                        const float r = extra[idx] + v;
                        ((float*)Cp)[idx] = r;
                        C2[idx] = r;
                    } else {
                        atomicAdd(((float*)Cp) + idx, v);
                    }
                }
            }
        }
    }
}

// ---------------------------------------------------------------------------
// Elementwise f32 -> bf16 (4 per thread)
// ---------------------------------------------------------------------------
__global__ void cvt_f32_bf16(const float* __restrict__ in, bf16* __restrict__ out, int n4)
{
    const int i = blockIdx.x * 256 + threadIdx.x;
    if (i < n4) {
        const float4 v = *(const float4*)&in[(long)i * 4];
        union { bf16 h[4]; ushort4 u; } o;
        o.h[0] = (bf16)v.x; o.h[1] = (bf16)v.y; o.h[2] = (bf16)v.z; o.h[3] = (bf16)v.w;
        *(ushort4*)&out[(long)i * 4] = o.u;
    }
}

// ---------------------------------------------------------------------------
// Transpose + cvt for 512x512 fp32 weight matrices (W[c][j] -> Wt[j][c] bf16)
// ---------------------------------------------------------------------------
__global__ __launch_bounds__(256)
void wtrans(const float* __restrict__ Wq, const float* __restrict__ Wk,
            const float* __restrict__ Wv, const float* __restrict__ Wo,
            bf16* __restrict__ wqkv_t, bf16* __restrict__ wo_t)
{
    __shared__ __align__(16) float T[64][68];
    const int z = blockIdx.z;
    const float* src = (z == 0) ? Wq : (z == 1) ? Wk : (z == 2) ? Wv : Wo;
    bf16* dst = (z < 3) ? (wqkv_t + (long)z * 262144) : wo_t;
    const int r0 = blockIdx.x * 64, c0 = blockIdx.y * 64;
    const int t  = threadIdx.x;
    const int rl = t >> 2;
    const int cq = (t & 3) * 16;
#pragma unroll
    for (int i = 0; i < 4; i++) {
        const float4 v = *(const float4*)&src[(long)(r0 + rl) * 512 + c0 + cq + i * 4];
        T[cq + i * 4 + 0][rl] = v.x;
        T[cq + i * 4 + 1][rl] = v.y;
        T[cq + i * 4 + 2][rl] = v.z;
        T[cq + i * 4 + 3][rl] = v.w;
    }
    __syncthreads();
#pragma unroll
    for (int i = 0; i < 4; i++) {
        const float4 v = *(const float4*)&T[rl][cq + i * 4];
        union { bf16 h[4]; ushort4 u; } o;
        o.h[0] = (bf16)v.x; o.h[1] = (bf16)v.y; o.h[2] = (bf16)v.z; o.h[3] = (bf16)v.w;
        *(ushort4*)&dst[(long)(c0 + rl) * 512 + r0 + cq + i * 4] = o.u;
    }
}

// ---------------------------------------------------------------------------
// Transpose V region of qkv (bf16): vt[b*512 + (j-1024)][l] = qkv[b*256+l][j]
// ---------------------------------------------------------------------------
__global__ __launch_bounds__(256)
void vtrans(const bf16* __restrict__ qkv, bf16* __restrict__ vt)
{
    __shared__ __align__(16) bf16 T[64][72];
    const int t  = threadIdx.x;
    const int l0 = blockIdx.x * 64, j0 = blockIdx.y * 64, b = blockIdx.z;
    const int r  = t >> 3;
    const int c8 = (t & 7) * 8;
#pragma unroll
    for (int p = 0; p < 2; p++) {
        const int rr = r + p * 32;
        bf16 v[8];
        *(uint4*)v = *(const uint4*)&qkv[(long)(b * 256 + l0 + rr) * 1536 + 1024 + j0 + c8];
#pragma unroll
        for (int i = 0; i < 8; i++) T[c8 + i][rr] = v[i];
    }
    __syncthreads();
#pragma unroll
    for (int p = 0; p < 2; p++) {
        const int rr = r + p * 32;
        const uint4 val = *(const uint4*)&T[rr][c8];
        *(uint4*)&vt[(long)(b * 512 + j0 + rr) * 256 + l0 + c8] = val;
    }
}

// ---------------------------------------------------------------------------
// Row softmax over 256-wide rows: one wave per row. S f32 -> P bf16.
// ---------------------------------------------------------------------------
__global__ __launch_bounds__(256)
void softmax_rows(const float* __restrict__ S, bf16* __restrict__ P)
{
    const int row  = blockIdx.x * 4 + (threadIdx.x >> 6);
    const int lane = threadIdx.x & 63;
    const float4 v = *(const float4*)&S[(long)row * 256 + lane * 4];
    float m = fmaxf(fmaxf(v.x, v.y), fmaxf(v.z, v.w));
#pragma unroll
    for (int off = 1; off < 64; off <<= 1) m = fmaxf(m, __shfl_xor(m, off));
    const float e0 = __expf(v.x - m), e1 = __expf(v.y - m);
    const float e2 = __expf(v.z - m), e3 = __expf(v.w - m);
    float s = e0 + e1 + e2 + e3;
#pragma unroll
    for (int off = 1; off < 64; off <<= 1) s += __shfl_xor(s, off);
    const float inv = 1.0f / s;
    union { bf16 h[4]; ushort4 u; } o;
    o.h[0] = (bf16)(e0 * inv); o.h[1] = (bf16)(e1 * inv);
    o.h[2] = (bf16)(e2 * inv); o.h[3] = (bf16)(e3 * inv);
    *(ushort4*)&P[(long)row * 256 + lane * 4] = o.u;
}

// ---------------------------------------------------------------------------
// im2col scatter helper: pooled value (b,lp,c) -> 3 ic slots + boundary zeros
// ic layout: [32*Ld][1536], entry (l, ci*3+t) = pooled[l+t-1] (0 if OOB)
// ---------------------------------------------------------------------------
__device__ inline void ic_scatter(bf16* __restrict__ icb, int lp, int Ld, float pooled)
{
    const bf16 pb = (bf16)pooled;
    icb[(long)lp * 1536 + 1] = pb;
    if (lp + 1 < Ld) icb[(long)(lp + 1) * 1536] = pb;
    if (lp > 0)      icb[(long)(lp - 1) * 1536 + 2] = pb;
    if (lp == 0)      icb[0] = (bf16)0.f;
    if (lp == Ld - 1) icb[(long)(Ld - 1) * 1536 + 2] = (bf16)0.f;
}

// ---------------------------------------------------------------------------
// depth-0 head of cascade: pool(k=2) from sf + im2col + zero conv accumulator
// one thread per pooled element (32*128*512 = 2M)
// ---------------------------------------------------------------------------
__global__ void cascade_first(const float* __restrict__ sf,
                              bf16* __restrict__ ic,
                              float* __restrict__ convz)
{
    const int idx = blockIdx.x * 256 + threadIdx.x;
    const int c  = idx & 511;
    const int lp = (idx >> 9) & 127;
    const int b  = idx >> 16;
    const float* p = sf + (long)(b * 256 + lp * 2) * 512 + c;
    const float pooled = (p[0] + p[512]) * 0.5f;
    convz[idx] = 0.f;
    ic_scatter(ic + (long)b * 128 * 1536 + (long)c * 3, lp, 128, pooled);
}

// ---------------------------------------------------------------------------
// depth d>=1: upsample(conv_{d-1})+bias+relu -> sf writeback -> pool(k) ->
// im2col -> zero conv accumulator. One thread per pooled element (32*Ld*512).
// ---------------------------------------------------------------------------
__global__ void cascade_mid(const float* __restrict__ conv,
                            const float* __restrict__ bias_p,
                            float* __restrict__ sf,
                            bf16* __restrict__ ic,
                            float* __restrict__ convz,
                            int ldshift, int k, float invk, float scale)
{
    const int idx = blockIdx.x * 256 + threadIdx.x;
    const int Ld = 1 << ldshift;
    const int c  = idx & 511;
    const int lp = (idx >> 9) & (Ld - 1);
    const int b  = idx >> (9 + ldshift);
    const int Lprev = Ld << 1;
    const float bias = bias_p[c];
    float* sfp = sf + ((long)b * 256 + (long)lp * k) * 512 + c;
    const float* cvb = conv + (long)b * Lprev * 512 + c;
    float s = 0.f;
    for (int i = 0; i < k; i++) {
        const int j = lp * k + i;
        float coords = (j + 0.5f) * scale - 0.5f;
        coords = fminf(fmaxf(coords, 0.f), (float)(Lprev - 1));
        const int lo = (int)coords;
        const int hi2 = min(lo + 1, Lprev - 1);
        const float w = coords - (float)lo;
        const float vlo = fmaxf(cvb[(long)lo * 512] + bias, 0.f);
        const float vhi = fmaxf(cvb[(long)hi2 * 512] + bias, 0.f);
        const float v = sfp[(long)i * 512] + vlo * (1.f - w) + vhi * w;
        sfp[(long)i * 512] = v;
        s += v;
    }
    convz[idx] = 0.f;
    ic_scatter(ic + (long)b * Ld * 1536 + (long)c * 3, lp, Ld, s * invk);
}

// ---------------------------------------------------------------------------
// final: out = attn_out + sf + upsample(relu(conv5 + bias))
// ---------------------------------------------------------------------------
__global__ void upsample_final(const float* __restrict__ conv,
                               const float* __restrict__ bias_p,
                               const float* __restrict__ sf,
                               float* __restrict__ outp)
{
    const int idx = blockIdx.x * 256 + threadIdx.x;
    const int c = idx & 511;
    const int j = (idx >> 9) & 255;
    const int b = idx >> 17;
    const float bias = bias_p[c];
    float coords = (j + 0.5f) * (4.f / 256.f) - 0.5f;
    coords = fminf(fmaxf(coords, 0.f), 3.f);
    const int lo = (int)coords;
    const int hi2 = min(lo + 1, 3);
    const float w = coords - (float)lo;
    const long rb = (long)b * 4 * 512 + c;
    const float vlo = fmaxf(conv[rb + (long)lo * 512] + bias, 0.f);
    const float vhi = fmaxf(conv[rb + (long)hi2 * 512] + bias, 0.f);
    outp[idx] = outp[idx] + sf[idx] + vlo * (1.f - w) + vhi * w;
}

// ---------------------------------------------------------------------------
// workspace layout (bytes)
// ---------------------------------------------------------------------------
static const long OFF_XB    = 0;          //  8,388,608  features bf16
static const long OFF_WQKV  = 8388608;    //  1,572,864  [1536][512] bf16
static const long OFF_WO    = 9961472;    //    524,288  [512][512] bf16
static const long OFF_WCONV = 10485760;   //  9,437,184  [6][512][1536] bf16
static const long OFF_QKV   = 19922944;   // 25,165,824  [8192][1536] bf16
static const long OFF_VT    = 45088768;   //  8,388,608  [32][512][256] bf16
static const long OFF_S     = 53477376;   // 67,108,864  [256][256][256] f32
static const long OFF_CTX   = 53477376;   //  (aliases S; S dead after softmax)
static const long OFF_IC    = 61865984;   // 12,582,912  (aliases S region)
static const long OFF_CONVA = 74448896;   //  8,388,608  (aliases S region)
static const long OFF_CONVB = 82837504;   //  4,194,304  (aliases S region)
static const long OFF_P     = 120586240;  // 33,554,432  [65536][256] bf16
static const long OFF_SF    = 154140672;  // 16,777,216  [8192][512] f32
// total: 170,917,888 bytes

extern "C" void kernel_launch(void* const* d_in, const int* in_sizes, int n_in,
                              void* d_out, int out_size, void* d_ws, size_t ws_size,
                              hipStream_t stream)
{
    const float* features = (const float*)d_in[0];
    const float* Wq = (const float*)d_in[1];
    const float* Wk = (const float*)d_in[2];
    const float* Wv = (const float*)d_in[3];
    const float* Wo = (const float*)d_in[4];
    const float* conv_w = (const float*)d_in[5];
    const float* conv_b = (const float*)d_in[6];
    float* out = (float*)d_out;

    char* ws = (char*)d_ws;
    bf16* xb     = (bf16*)(ws + OFF_XB);
    bf16* wqkv_t = (bf16*)(ws + OFF_WQKV);
    bf16* wo_t   = (bf16*)(ws + OFF_WO);
    bf16* wconv  = (bf16*)(ws + OFF_WCONV);
    bf16* qkv    = (bf16*)(ws + OFF_QKV);
    bf16* vt     = (bf16*)(ws + OFF_VT);
    float* Sbuf  = (float*)(ws + OFF_S);
    bf16* ctx    = (bf16*)(ws + OFF_CTX);
    bf16* ic     = (bf16*)(ws + OFF_IC);
    float* convA = (float*)(ws + OFF_CONVA);
    float* convB = (float*)(ws + OFF_CONVB);
    bf16* P      = (bf16*)(ws + OFF_P);
    float* sf    = (float*)(ws + OFF_SF);
    float* convbuf[2] = {convA, convB};

    // --- input conversions ---
    cvt_f32_bf16<<<4096, 256, 0, stream>>>(features, xb, 1048576);
    cvt_f32_bf16<<<4608, 256, 0, stream>>>(conv_w, wconv, 1179648);
    wtrans<<<dim3(8, 8, 4), 256, 0, stream>>>(Wq, Wk, Wv, Wo, wqkv_t, wo_t);

    // --- fused QKV projection: qkv[8192][1536] ---
    gemm_bt<0><<<dim3(768, 1, 1), 256, 0, stream>>>(
        xb, 512, 0, 0, wqkv_t, 512, 0, 0, qkv, 1536, 0, 0,
        8192, 1536, 512, 12, nullptr, 1.f, nullptr);

    // --- V transpose for PV GEMM ---
    vtrans<<<dim3(4, 8, 32), 256, 0, stream>>>(qkv, vt);

    // --- scores: S[bh][l][m] = (q . k)/8 , batched over 256 (b,h) ---
    gemm_bt<1><<<dim3(4, 256, 1), 256, 0, stream>>>(
        qkv, 1536, 393216, 64,
        qkv + 512, 1536, 393216, 64,
        Sbuf, 256, 524288, 65536,
        256, 256, 64, 2, nullptr, 0.125f, nullptr);

    // --- softmax rows -> P bf16 ---
    softmax_rows<<<16384, 256, 0, stream>>>(Sbuf, P);

    // --- ctx = P @ V : Bt = V^T (vt) ---
    gemm_bt<0><<<dim3(2, 256, 1), 256, 0, stream>>>(
        P, 256, 524288, 65536,
        vt, 256, 131072, 16384,
        ctx, 512, 131072, 64,
        256, 64, 256, 1, nullptr, 1.f, nullptr);

    // --- out_attn = features + ctx @ Wo  (dual store: d_out and sf) ---
    gemm_bt<2><<<dim3(256, 1, 1), 256, 0, stream>>>(
        ctx, 512, 0, 0, wo_t, 512, 0, 0, out, 512, 0, 0,
        8192, 512, 512, 4, features, 1.f, sf);

    // --- ScaleFeatures cascade ---
    static const int SPLITS[6] = {2, 4, 8, 12, 12, 12};

    // d = 0
    cascade_first<<<8192, 256, 0, stream>>>(sf, ic, convbuf[0]);
    gemm_bt<3><<<dim3(128, 1, SPLITS[0]), 256, 0, stream>>>(
        ic, 1536, 0, 0, wconv, 1536, 0, 0, convbuf[0], 512, 0, 0,
        4096, 512, 1536 / SPLITS[0], 4, nullptr, 1.f, nullptr);

    // d = 1..5
    for (int d = 1; d < 6; d++) {
        const int ldshift = 7 - d;
        const int Ld = 1 << ldshift;
        const int k  = 2 << d;
        cascade_mid<<<64 * Ld, 256, 0, stream>>>(
            convbuf[(d - 1) & 1], conv_b + (d - 1) * 512, sf, ic, convbuf[d & 1],
            ldshift, k, 1.0f / (float)k, (float)(2 * Ld) / 256.f);
        gemm_bt<3><<<dim3((Ld / 4) * 4, 1, SPLITS[d]), 256, 0, stream>>>(
            ic, 1536, 0, 0,
            wconv + (long)d * 786432, 1536, 0, 0,
            convbuf[d & 1], 512, 0, 0,
            32 * Ld, 512, 1536 / SPLITS[d], 4, nullptr, 1.f, nullptr);
    }

    // --- final: out = attn_out + sf + up(relu(conv5 + b5)) ---
    upsample_final<<<16384, 256, 0, stream>>>(
        convbuf[1], conv_b + 5 * 512, sf, out);
}